// Round 9
// baseline (231.730 us; speedup 1.0000x reference)
//
#include <hip/hip_runtime.h>
#include <stdint.h>

// Problem constants: B=2, Q=1024, N=4096, C=768, H=12, D=64, REL=32
// Inputs/outputs fp32 (established R1/R2).
typedef unsigned short ushort_t;
typedef __bf16 bf16x8 __attribute__((ext_vector_type(8)));
typedef float f32x4 __attribute__((ext_vector_type(4)));
typedef unsigned short us4 __attribute__((ext_vector_type(4)));

#define LOG2E 1.4426950408889634f
#define NEG8L (-11.541560327111707f)   // -8*log2(e)
#define QSCALE 0.18033688011110974f    // 0.125*log2(e)

__device__ __forceinline__ ushort_t f2b(float f) {
    unsigned u = __float_as_uint(f);
    unsigned r = (u + 0x7fffu + ((u >> 16) & 1u)) >> 16;
    return (ushort_t)r;
}
__device__ __forceinline__ void gld16(const void* g, void* l) {
    __builtin_amdgcn_global_load_lds(
        (__attribute__((address_space(1))) void*)g,
        (__attribute__((address_space(3))) void*)l,
        16, 0, 0);
}

// ------------------------------------------------------------ fused prep
__global__ __launch_bounds__(256) void prep(
        const float* __restrict__ query, const float* __restrict__ keyv,
        const float* __restrict__ Wq, const float* __restrict__ Wk,
        const float* __restrict__ Wv, const float* __restrict__ Wo,
        const float* __restrict__ rel,
        ushort_t* __restrict__ qc, ushort_t* __restrict__ kvc,
        ushort_t* __restrict__ wtq, ushort_t* __restrict__ wtk,
        ushort_t* __restrict__ wtv, ushort_t* __restrict__ wto,
        ushort_t* __restrict__ b1b, ushort_t* __restrict__ wtab) {
    __shared__ ushort_t tsh[32][33];
    const int bid = blockIdx.x, tid = threadIdx.x;
    if (bid < 7680) {
        const float* src = (bid < 1536) ? query : keyv;
        ushort_t* dst = (bid < 1536) ? qc : kvc;
        int i = ((bid < 1536) ? bid : bid - 1536) * 256 + tid;
        float4 x = ((const float4*)src)[i];
        us4 v; v.x = f2b(x.x); v.y = f2b(x.y); v.z = f2b(x.z); v.w = f2b(x.w);
        ((us4*)dst)[i] = v;
    } else if (bid < 9984) {
        int t = bid - 7680, w = t / 576, tt = t - w * 576;
        const float* in = (w == 0) ? Wq : (w == 1) ? Wk : (w == 2) ? Wv : Wo;
        ushort_t* out = (w == 0) ? wtq : (w == 1) ? wtk : (w == 2) ? wtv : wto;
        int x = tid & 31, y = tid >> 5;
        int bx = (tt % 24) * 32, by = (tt / 24) * 32;
#pragma unroll
        for (int j = 0; j < 32; j += 8)
            tsh[y + j][x] = f2b(in[(size_t)(by + y + j) * 768 + bx + x]);
        __syncthreads();
#pragma unroll
        for (int j = 0; j < 32; j += 8)
            out[(size_t)(bx + y + j) * 768 + by + x] = tsh[x][y + j];
    } else if (bid < 11520) {
        int idx = (bid - 9984) * 256 + tid;
        int j = idx & 31, q = (idx >> 5) & 1023, h = idx >> 15;
        float pos = q * (31.0f / 1023.0f);
        float fl = floorf(pos);
        int lo = (int)fl; if (lo > 31) lo = 31;
        float w = pos - fl;
        int hi = lo + 1; if (hi > 31) hi = 31;
        float vlo = rel[(h * 32 + lo) * 32 + j];
        float vhi = rel[(h * 32 + hi) * 32 + j];
        b1b[idx] = f2b((vlo + (vhi - vlo) * w) * LOG2E);
    } else {
        int n = (bid - 11520) * 256 + tid;
        float pos = n * (31.0f / 4095.0f);
        float fl = floorf(pos);
        int ln = (int)fl; if (ln > 31) ln = 31;
        float wn = pos - fl;
        int hn = ln + 1; if (hn > 31) hn = 31;
        float vals[32];
#pragma unroll
        for (int j = 0; j < 32; ++j) vals[j] = 0.f;
        vals[ln] += 1.0f - wn;
        vals[hn] += wn;
#pragma unroll
        for (int j = 0; j < 32; ++j) wtab[n * 32 + j] = f2b(vals[j]);
    }
}

// ------------------------------------------------- epilogue store (shared)
// mode 2: A=activations(m), B=weights(n): V^T layout, us4 over act-rows
// mode 3: A=weights(m), B=activations(n): C^T head-split, us4 over d
// mode 4: A=weights(m), B=activations(n): fp32 float4 over out-cols
__device__ __forceinline__ void gemm_store(const float* __restrict__ bias,
                                           f32x4 a, void* out,
                                           int mode, int lsh, float scale,
                                           int mbase, int n) {
    if (mode == 2) {
        int h = n >> 6, d = n & 63;
        int b = mbase >> lsh, l = mbase & ((1 << lsh) - 1);
        float bvf = bias[n];
        us4 v;
        v.x = f2b((a[0] + bvf) * scale);
        v.y = f2b((a[1] + bvf) * scale);
        v.z = f2b((a[2] + bvf) * scale);
        v.w = f2b((a[3] + bvf) * scale);
        *(us4*)((ushort_t*)out + ((size_t)((b * 12 + h) * 64 + d) << lsh) + l) = v;
    } else if (mode == 3) {
        int h = mbase >> 6, dbase = mbase & 63;
        int b = n >> lsh, l = n & ((1 << lsh) - 1);
        us4 v;
        v.x = f2b((a[0] + bias[mbase + 0]) * scale);
        v.y = f2b((a[1] + bias[mbase + 1]) * scale);
        v.z = f2b((a[2] + bias[mbase + 2]) * scale);
        v.w = f2b((a[3] + bias[mbase + 3]) * scale);
        *(us4*)((ushort_t*)out + ((((size_t)(b * 12 + h) << lsh) + l) << 6) + dbase) = v;
    } else {  // mode 4
        float4 v;
        v.x = (a[0] + bias[mbase + 0]) * scale;
        v.y = (a[1] + bias[mbase + 1]) * scale;
        v.z = (a[2] + bias[mbase + 2]) * scale;
        v.w = (a[3] + bias[mbase + 3]) * scale;
        *(float4*)((float*)out + (size_t)n * 768 + mbase) = v;
    }
}

// ---------------- 128x128 GEMM body, BK=32, double-buffered LDS prefetch.
// Per round: __syncthreads (drains round-i loads after a full compute phase
// of overlap), issue round i+1 into the other buffer, compute round i.
__device__ __forceinline__ void gemm_body128(const ushort_t* __restrict__ A,
                                             const ushort_t* __restrict__ Bt,
                                             const float* __restrict__ bias,
                                             void* __restrict__ out,
                                             int mode, int lsh, float scale,
                                             int m0, int n0,
                                             ushort_t* As, ushort_t* Bs, int tid) {
    const int wave = tid >> 6, lane = tid & 63;
    const int quad = lane >> 4, l15 = lane & 15;
    const int wm = wave >> 1, wn = wave & 1;
    const f32x4 z4 = {0.f, 0.f, 0.f, 0.f};
    f32x4 acc[4][4];
#pragma unroll
    for (int i = 0; i < 4; ++i)
#pragma unroll
        for (int j = 0; j < 4; ++j) acc[i][j] = z4;

    const int lrow = lane >> 2;                       // row-in-chunk 0..15
    const int kswz = ((lane & 3) ^ (lrow & 3)) * 8;   // swizzled 16B block

    // issue one 32-wide k-slab into buffer `buf`
    auto issue = [&](int kk, int buf) {
#pragma unroll
        for (int i = 0; i < 2; ++i) {
            int c = wave * 2 + i;                      // chunk 0..7 (16 rows)
            gld16(A + (size_t)(m0 + c * 16 + lrow) * 768 + kk + kswz,
                  (void*)(As + buf * 4096 + c * 512));
            gld16(Bt + (size_t)(n0 + c * 16 + lrow) * 768 + kk + kswz,
                  (void*)(Bs + buf * 4096 + c * 512));
        }
    };

    issue(0, 0);
    for (int it = 0; it < 24; ++it) {
        __syncthreads();
        if (it + 1 < 24) issue((it + 1) * 32, (it + 1) & 1);
        const ushort_t* Ab = As + (it & 1) * 4096;
        const ushort_t* Bb = Bs + (it & 1) * 4096;
        bf16x8 af[4], bf[4];
#pragma unroll
        for (int mb = 0; mb < 4; ++mb) {
            int r = wm * 64 + mb * 16 + l15;
            af[mb] = *(const bf16x8*)(Ab + r * 32 + ((quad ^ (r & 3)) * 8));
        }
#pragma unroll
        for (int nb = 0; nb < 4; ++nb) {
            int r = wn * 64 + nb * 16 + l15;
            bf[nb] = *(const bf16x8*)(Bb + r * 32 + ((quad ^ (r & 3)) * 8));
        }
#pragma unroll
        for (int mb = 0; mb < 4; ++mb)
#pragma unroll
            for (int nb = 0; nb < 4; ++nb)
                acc[mb][nb] = __builtin_amdgcn_mfma_f32_16x16x32_bf16(af[mb], bf[nb], acc[mb][nb], 0, 0, 0);
    }

#pragma unroll
    for (int mb = 0; mb < 4; ++mb) {
        int mbase = m0 + wm * 64 + mb * 16 + quad * 4;
#pragma unroll
        for (int nb = 0; nb < 4; ++nb) {
            int n = n0 + wn * 64 + nb * 16 + l15;
            gemm_store(bias, acc[mb][nb], out, mode, lsh, scale, mbase, n);
        }
    }
}

// ------------------ 64x64 GEMM body, BK=32, double-buffered (out-proj)
__device__ __forceinline__ void gemm_body64(const ushort_t* __restrict__ A,
                                            const ushort_t* __restrict__ Bt,
                                            const float* __restrict__ bias,
                                            void* __restrict__ out,
                                            int mode, int lsh, float scale,
                                            int m0, int n0,
                                            ushort_t* As, ushort_t* Bs, int tid) {
    const int wave = tid >> 6, lane = tid & 63;
    const int quad = lane >> 4, l15 = lane & 15;
    const f32x4 z4 = {0.f, 0.f, 0.f, 0.f};
    f32x4 acc[4];
#pragma unroll
    for (int j = 0; j < 4; ++j) acc[j] = z4;

    const int lrow = lane >> 2;
    const int kswz = ((lane & 3) ^ (lrow & 3)) * 8;

    auto issue = [&](int kk, int buf) {
        gld16(A + (size_t)(m0 + wave * 16 + lrow) * 768 + kk + kswz,
              (void*)(As + buf * 2048 + wave * 512));
        gld16(Bt + (size_t)(n0 + wave * 16 + lrow) * 768 + kk + kswz,
              (void*)(Bs + buf * 2048 + wave * 512));
    };

    issue(0, 0);
    for (int it = 0; it < 24; ++it) {
        __syncthreads();
        if (it + 1 < 24) issue((it + 1) * 32, (it + 1) & 1);
        const ushort_t* Ab = As + (it & 1) * 2048;
        const ushort_t* Bb = Bs + (it & 1) * 2048;
        bf16x8 af, bf[4];
        {
            int r = wave * 16 + l15;
            af = *(const bf16x8*)(Ab + r * 32 + ((quad ^ (r & 3)) * 8));
        }
#pragma unroll
        for (int nb = 0; nb < 4; ++nb) {
            int r = nb * 16 + l15;
            bf[nb] = *(const bf16x8*)(Bb + r * 32 + ((quad ^ (r & 3)) * 8));
        }
#pragma unroll
        for (int nb = 0; nb < 4; ++nb)
            acc[nb] = __builtin_amdgcn_mfma_f32_16x16x32_bf16(af, bf[nb], acc[nb], 0, 0, 0);
    }

    int mbase = m0 + wave * 16 + quad * 4;
#pragma unroll
    for (int nb = 0; nb < 4; ++nb) {
        int n = n0 + nb * 16 + l15;
        gemm_store(bias, acc[nb], out, mode, lsh, scale, mbase, n);
    }
}

// ------------------------------------------ fused Q/K/V projections, 128x128
__global__ __launch_bounds__(256) void proj3(const ushort_t* __restrict__ qc,
                                             const ushort_t* __restrict__ kvc,
                                             const ushort_t* __restrict__ wtq,
                                             const ushort_t* __restrict__ wtk,
                                             const ushort_t* __restrict__ wtv,
                                             const float* __restrict__ bq,
                                             const float* __restrict__ bk,
                                             const float* __restrict__ bv,
                                             ushort_t* __restrict__ qp,
                                             ushort_t* __restrict__ kp,
                                             ushort_t* __restrict__ vtp) {
    __shared__ __align__(16) ushort_t As[2 * 128 * 32];
    __shared__ __align__(16) ushort_t Bs[2 * 128 * 32];
    const int bid = blockIdx.x, tid = threadIdx.x;
    if (bid < 96) {            // Q: A=wtq, B=qc(2048 rows)
        int t = bid;
        int nt = (t & 7) + 8 * ((t >> 3) & 1), mt = t >> 4;
        gemm_body128(wtq, qc, bq, qp, 3, 10, QSCALE, mt * 128, nt * 128, As, Bs, tid);
    } else if (bid < 480) {    // K: A=wtk, B=kvc(8192 rows)
        int t = bid - 96;
        int nt = (t & 7) + 8 * ((t >> 3) & 7), mt = t >> 6;
        gemm_body128(wtk, kvc, bk, kp, 3, 12, 1.0f, mt * 128, nt * 128, As, Bs, tid);
    } else {                   // V: A=kvc(8192 rows), B=wtv
        int t = bid - 480, mt = t & 63, nt = t >> 6;
        gemm_body128(kvc, wtv, bv, vtp, 2, 12, 1.0f, mt * 128, nt * 128, As, Bs, tid);
    }
}

// ------------------------------------------------------------ output GEMM
__global__ __launch_bounds__(256) void gemm_out(const ushort_t* __restrict__ ab,
                                                const ushort_t* __restrict__ wto,
                                                const float* __restrict__ bo,
                                                float* __restrict__ out) {
    __shared__ __align__(16) ushort_t As[2 * 64 * 32];
    __shared__ __align__(16) ushort_t Bs[2 * 64 * 32];
    const int bid = blockIdx.x, tid = threadIdx.x;
    int j = bid >> 3;
    int nt = (bid & 7) + 8 * (j & 3), mt = j >> 2;   // nt 0..31, mt 0..11
    gemm_body64(wto, ab, bo, out, 4, 0, 1.0f, mt * 64, nt * 64, As, Bs, tid);
}

// -------------------------- flash attention, N-split x 2, dbuf k/v prefetch
// 768 blocks. XCD pin: xcd=bid&7, 3 (b,h) groups/XCD. Per block: 64 q rows,
// 2048 n (32 rounds). K/V staged into alternating LDS buffers; the barrier
// drain lands after a full compute round of load latency hiding.
__global__ __launch_bounds__(256) void attn64s(const ushort_t* __restrict__ qp,
                                               const ushort_t* __restrict__ kp,
                                               const ushort_t* __restrict__ vt,
                                               const ushort_t* __restrict__ b1b,
                                               const ushort_t* __restrict__ wtab,
                                               float* __restrict__ po,
                                               float* __restrict__ pl) {
    __shared__ __align__(16) ushort_t k_s[2 * 64 * 64];
    __shared__ __align__(16) ushort_t v_s[2 * 64 * 64];
    __shared__ __align__(16) float pf[4][576];   // per-wave 32 cols x stride 18

    const int tid = threadIdx.x;
    const int wave = tid >> 6, lane = tid & 63;
    const int quad = lane >> 4, l15 = lane & 15;
    const int bid = blockIdx.x;
    const int xcd = bid & 7;
    const int slot = bid >> 3;           // 0..95
    const int g = xcd + 8 * (slot >> 5); // (b,h) group 0..23, pinned to xcd
    const int member = slot & 31;        // 0..31
    const int b = g / 12, h = g - b * 12;
    const int qt = member & 15, sp = member >> 4;   // sp 0..1
    const int q0 = qt * 64;
    const int bh = g;

    const ushort_t* qg = qp + ((size_t)bh * 1024 + q0) * 64;
    const ushort_t* kg = kp + (size_t)bh * 4096 * 64;
    const ushort_t* vg = vt + (size_t)bh * 64 * 4096;

    const int rowq = wave * 16 + l15;
    bf16x8 aq[2];
#pragma unroll
    for (int ks = 0; ks < 2; ++ks)
        aq[ks] = *(const bf16x8*)(qg + (size_t)rowq * 64 + (ks * 4 + quad) * 8);
    bf16x8 ab1 = *(const bf16x8*)(b1b + ((size_t)(h * 1024 + q0 + rowq)) * 32 + quad * 8);

    const f32x4 mC = {NEG8L, NEG8L, NEG8L, NEG8L};
    const f32x4 z4 = {0.f, 0.f, 0.f, 0.f};
    f32x4 o[4];
    float lsum[4];
#pragma unroll
    for (int d = 0; d < 4; ++d) o[d] = z4;
#pragma unroll
    for (int r = 0; r < 4; ++r) lsum[r] = 0.f;

    const int arow = lane >> 3;
    const int ablk = lane & 7;
    const int nbase = sp * 2048;

    auto issueKV = [&](int nt, int buf) {
        const int n0 = nbase + nt * 64;
#pragma unroll
        for (int i = 0; i < 2; ++i) {
            int c = wave * 2 + i;
            int row = c * 8 + arow;
            int k16 = ablk ^ (row & 7);
            gld16(kg + (size_t)(n0 + row) * 64 + k16 * 8, (void*)(k_s + buf * 4096 + c * 512));
            gld16(vg + (size_t)row * 4096 + n0 + k16 * 8, (void*)(v_s + buf * 4096 + c * 512));
        }
    };

    issueKV(0, 0);
    for (int nt = 0; nt < 32; ++nt) {
        __syncthreads();
        if (nt + 1 < 32) issueKV(nt + 1, (nt + 1) & 1);
        const ushort_t* kb = k_s + (nt & 1) * 4096;
        const ushort_t* vb = v_s + (nt & 1) * 4096;
        const int n0 = nbase + nt * 64;

        bf16x8 wf[4];
#pragma unroll
        for (int nb = 0; nb < 4; ++nb)
            wf[nb] = *(const bf16x8*)(wtab + (size_t)(n0 + nb * 16 + l15) * 32 + quad * 8);

        // s = log2e*(qk*0.125 + bias) - 8*log2e
        f32x4 s[4];
#pragma unroll
        for (int nb = 0; nb < 4; ++nb) {
            s[nb] = __builtin_amdgcn_mfma_f32_16x16x32_bf16(ab1, wf[nb], mC, 0, 0, 0);
#pragma unroll
            for (int ks = 0; ks < 2; ++ks) {
                int rn = nb * 16 + l15;
                bf16x8 bk = *(const bf16x8*)(kb + rn * 64 + (((ks * 4 + quad) ^ (rn & 7)) * 8));
                s[nb] = __builtin_amdgcn_mfma_f32_16x16x32_bf16(aq[ks], bk, s[nb], 0, 0, 0);
            }
        }
#pragma unroll
        for (int nb = 0; nb < 4; ++nb)
#pragma unroll
            for (int r = 0; r < 4; ++r) {
                float p = exp2f(s[nb][r]);
                s[nb][r] = p;
                lsum[r] += p;
            }
        // P transpose: C-layout fp32 -> wave-private LDS (stride 18) -> A-layout
#pragma unroll
        for (int p = 0; p < 2; ++p) {
#pragma unroll
            for (int i = 0; i < 2; ++i) {
                int nb = 2 * p + i;
                float* dst = &pf[wave][(i * 16 + l15) * 18 + quad * 4];
                *(float2*)dst = make_float2(s[nb][0], s[nb][1]);
                *(float2*)(dst + 2) = make_float2(s[nb][2], s[nb][3]);
            }
            bf16x8 ap;
#pragma unroll
            for (int j = 0; j < 8; ++j)
                ap[j] = (__bf16)pf[wave][(quad * 8 + j) * 18 + l15];
#pragma unroll
            for (int d = 0; d < 4; ++d) {
                int rd = d * 16 + l15;
                bf16x8 bv = *(const bf16x8*)(vb + rd * 64 + (((p * 4 + quad) ^ (rd & 7)) * 8));
                o[d] = __builtin_amdgcn_mfma_f32_16x16x32_bf16(ap, bv, o[d], 0, 0, 0);
            }
        }
    }

#pragma unroll
    for (int r = 0; r < 4; ++r)
#pragma unroll
        for (int off = 1; off < 16; off <<= 1)
            lsum[r] += __shfl_xor(lsum[r], off, 64);

    const size_t pbase = ((size_t)(sp * 24 + bh)) * 1024;
#pragma unroll
    for (int r = 0; r < 4; ++r) {
        int qrow = q0 + wave * 16 + quad * 4 + r;
        if (l15 == 0) pl[pbase + qrow] = lsum[r];
#pragma unroll
        for (int d = 0; d < 4; ++d)
            po[(pbase + qrow) * 64 + d * 16 + l15] = o[d][r];
    }
}

// ----------------------------------------------------------- split combine
__global__ __launch_bounds__(256) void combine(const float* __restrict__ po,
                                               const float* __restrict__ pl,
                                               ushort_t* __restrict__ ab) {
    int idx = blockIdx.x * 256 + threadIdx.x;
    int e = idx * 4;
    int b = e / 786432;
    int rem = e - b * 786432;
    int q = rem / 768;
    int col = rem - q * 768;
    int h = col >> 6, d = col & 63;
    int bh = b * 12 + h;
    float4 acc = {0.f, 0.f, 0.f, 0.f};
    float l = 0.f;
#pragma unroll
    for (int s = 0; s < 2; ++s) {
        size_t base = ((size_t)(s * 24 + bh)) * 1024 + q;
        float4 v = *(const float4*)(po + base * 64 + d);
        acc.x += v.x; acc.y += v.y; acc.z += v.z; acc.w += v.w;
        l += pl[base];
    }
    float inv = 1.0f / l;
    us4 v;
    v.x = f2b(acc.x * inv); v.y = f2b(acc.y * inv);
    v.z = f2b(acc.z * inv); v.w = f2b(acc.w * inv);
    *(us4*)(ab + (size_t)(b * 1024 + q) * 768 + col) = v;
}

// ------------------------------------------------------------------- launch
extern "C" void kernel_launch(void* const* d_in, const int* in_sizes, int n_in,
                              void* d_out, int out_size, void* d_ws, size_t ws_size,
                              hipStream_t stream) {
    const float* query = (const float*)d_in[0];
    const float* keyv  = (const float*)d_in[1];
    const float* Wq = (const float*)d_in[2];
    const float* bq = (const float*)d_in[3];
    const float* Wk = (const float*)d_in[4];
    const float* bk = (const float*)d_in[5];
    const float* Wv = (const float*)d_in[6];
    const float* bv = (const float*)d_in[7];
    const float* Wo = (const float*)d_in[8];
    const float* bo = (const float*)d_in[9];
    const float* rel = (const float*)d_in[10];

    char* ws = (char*)d_ws;
    ushort_t* qc   = (ushort_t*)(ws + 0);
    ushort_t* kvc  = (ushort_t*)(ws + 3145728);
    ushort_t* wtq  = (ushort_t*)(ws + 15728640);
    ushort_t* wtk  = (ushort_t*)(ws + 16908288);
    ushort_t* wtv  = (ushort_t*)(ws + 18087936);
    ushort_t* wto  = (ushort_t*)(ws + 19267584);
    ushort_t* qp   = (ushort_t*)(ws + 20447232);  // [B,H,Q,64] bf16 (x0.125*log2e)
    ushort_t* kp   = (ushort_t*)(ws + 23592960);  // [B,H,N,64] bf16
    ushort_t* vtp  = (ushort_t*)(ws + 36175872);  // [B,H,64,N] bf16
    ushort_t* b1b  = (ushort_t*)(ws + 48758784);  // [H,Q,32] bf16 (x log2e)
    ushort_t* wtab = (ushort_t*)(ws + 49545216);  // [N,32] bf16
    ushort_t* ab   = (ushort_t*)(ws + 49807360);  // [B,Q,768] bf16
    float*    po   = (float*)(ws + 52953088);     // [2,B*H,Q,64] f32 (12.6 MB)
    float*    pl   = (float*)(ws + 65536000);     // [2,B*H,Q] f32
    // total ws usage: ~65.7 MB

    prep<<<11536, 256, 0, stream>>>(query, keyv, Wq, Wk, Wv, Wo, rel,
                                    qc, kvc, wtq, wtk, wtv, wto, b1b, wtab);
    proj3<<<864, 256, 0, stream>>>(qc, kvc, wtq, wtk, wtv, bq, bk, bv, qp, kp, vtp);
    attn64s<<<768, 256, 0, stream>>>(qp, kp, vtp, b1b, wtab, po, pl);
    combine<<<1536, 256, 0, stream>>>(po, pl, ab);
    gemm_out<<<384, 256, 0, stream>>>(ab, wto, bo, (float*)d_out);
}

// Round 10
// 218.406 us; speedup vs baseline: 1.0610x; 1.0610x over previous
//
#include <hip/hip_runtime.h>
#include <stdint.h>

// Problem constants: B=2, Q=1024, N=4096, C=768, H=12, D=64, REL=32
// Inputs/outputs fp32 (established R1/R2).
typedef unsigned short ushort_t;
typedef __bf16 bf16x8 __attribute__((ext_vector_type(8)));
typedef __bf16 bf16x4v __attribute__((ext_vector_type(4)));
typedef float f32x4 __attribute__((ext_vector_type(4)));
typedef unsigned short us4 __attribute__((ext_vector_type(4)));

#define LOG2E 1.4426950408889634f
#define NEG8L (-11.541560327111707f)   // -8*log2(e)
#define QSCALE 0.18033688011110974f    // 0.125*log2(e)

__device__ __forceinline__ ushort_t f2b(float f) {
    unsigned u = __float_as_uint(f);
    unsigned r = (u + 0x7fffu + ((u >> 16) & 1u)) >> 16;
    return (ushort_t)r;
}
__device__ __forceinline__ void gld16(const void* g, void* l) {
    __builtin_amdgcn_global_load_lds(
        (__attribute__((address_space(1))) void*)g,
        (__attribute__((address_space(3))) void*)l,
        16, 0, 0);
}

// ------------------------------------------------------------ fused prep
__global__ __launch_bounds__(256) void prep(
        const float* __restrict__ query, const float* __restrict__ keyv,
        const float* __restrict__ Wq, const float* __restrict__ Wk,
        const float* __restrict__ Wv, const float* __restrict__ Wo,
        const float* __restrict__ rel,
        ushort_t* __restrict__ qc, ushort_t* __restrict__ kvc,
        ushort_t* __restrict__ wtq, ushort_t* __restrict__ wtk,
        ushort_t* __restrict__ wtv, ushort_t* __restrict__ wto,
        ushort_t* __restrict__ b1b, ushort_t* __restrict__ wtab) {
    __shared__ ushort_t tsh[32][33];
    const int bid = blockIdx.x, tid = threadIdx.x;
    if (bid < 7680) {
        const float* src = (bid < 1536) ? query : keyv;
        ushort_t* dst = (bid < 1536) ? qc : kvc;
        int i = ((bid < 1536) ? bid : bid - 1536) * 256 + tid;
        float4 x = ((const float4*)src)[i];
        us4 v; v.x = f2b(x.x); v.y = f2b(x.y); v.z = f2b(x.z); v.w = f2b(x.w);
        ((us4*)dst)[i] = v;
    } else if (bid < 9984) {
        int t = bid - 7680, w = t / 576, tt = t - w * 576;
        const float* in = (w == 0) ? Wq : (w == 1) ? Wk : (w == 2) ? Wv : Wo;
        ushort_t* out = (w == 0) ? wtq : (w == 1) ? wtk : (w == 2) ? wtv : wto;
        int x = tid & 31, y = tid >> 5;
        int bx = (tt % 24) * 32, by = (tt / 24) * 32;
#pragma unroll
        for (int j = 0; j < 32; j += 8)
            tsh[y + j][x] = f2b(in[(size_t)(by + y + j) * 768 + bx + x]);
        __syncthreads();
#pragma unroll
        for (int j = 0; j < 32; j += 8)
            out[(size_t)(bx + y + j) * 768 + by + x] = tsh[x][y + j];
    } else if (bid < 11520) {
        int idx = (bid - 9984) * 256 + tid;
        int j = idx & 31, q = (idx >> 5) & 1023, h = idx >> 15;
        float pos = q * (31.0f / 1023.0f);
        float fl = floorf(pos);
        int lo = (int)fl; if (lo > 31) lo = 31;
        float w = pos - fl;
        int hi = lo + 1; if (hi > 31) hi = 31;
        float vlo = rel[(h * 32 + lo) * 32 + j];
        float vhi = rel[(h * 32 + hi) * 32 + j];
        b1b[idx] = f2b((vlo + (vhi - vlo) * w) * LOG2E);
    } else {
        int n = (bid - 11520) * 256 + tid;
        float pos = n * (31.0f / 4095.0f);
        float fl = floorf(pos);
        int ln = (int)fl; if (ln > 31) ln = 31;
        float wn = pos - fl;
        int hn = ln + 1; if (hn > 31) hn = 31;
        float vals[32];
#pragma unroll
        for (int j = 0; j < 32; ++j) vals[j] = 0.f;
        vals[ln] += 1.0f - wn;
        vals[hn] += wn;
#pragma unroll
        for (int j = 0; j < 32; ++j) wtab[n * 32 + j] = f2b(vals[j]);
    }
}

// ------------------------------------------------- epilogue store (shared)
// mode 2: A=activations(m), B=weights(n): V^T layout, us4 over act-rows
// mode 3: A=weights(m), B=activations(n): C^T head-split, us4 over d
// mode 4: A=weights(m), B=activations(n): fp32 float4 over out-cols
__device__ __forceinline__ void gemm_store(const float* __restrict__ bias,
                                           f32x4 a, void* out,
                                           int mode, int lsh, float scale,
                                           int mbase, int n) {
    if (mode == 2) {
        int h = n >> 6, d = n & 63;
        int b = mbase >> lsh, l = mbase & ((1 << lsh) - 1);
        float bvf = bias[n];
        us4 v;
        v.x = f2b((a[0] + bvf) * scale);
        v.y = f2b((a[1] + bvf) * scale);
        v.z = f2b((a[2] + bvf) * scale);
        v.w = f2b((a[3] + bvf) * scale);
        *(us4*)((ushort_t*)out + ((size_t)((b * 12 + h) * 64 + d) << lsh) + l) = v;
    } else if (mode == 3) {
        int h = mbase >> 6, dbase = mbase & 63;
        int b = n >> lsh, l = n & ((1 << lsh) - 1);
        us4 v;
        v.x = f2b((a[0] + bias[mbase + 0]) * scale);
        v.y = f2b((a[1] + bias[mbase + 1]) * scale);
        v.z = f2b((a[2] + bias[mbase + 2]) * scale);
        v.w = f2b((a[3] + bias[mbase + 3]) * scale);
        *(us4*)((ushort_t*)out + ((((size_t)(b * 12 + h) << lsh) + l) << 6) + dbase) = v;
    } else {  // mode 4
        float4 v;
        v.x = (a[0] + bias[mbase + 0]) * scale;
        v.y = (a[1] + bias[mbase + 1]) * scale;
        v.z = (a[2] + bias[mbase + 2]) * scale;
        v.w = (a[3] + bias[mbase + 3]) * scale;
        *(float4*)((float*)out + (size_t)n * 768 + mbase) = v;
    }
}

// --------------------------------------- 128x128 GEMM body, BK=64 (K=768)
// (R8-proven single-buffer version; dbuf regressed in R9.)
__device__ __forceinline__ void gemm_body128(const ushort_t* __restrict__ A,
                                             const ushort_t* __restrict__ Bt,
                                             const float* __restrict__ bias,
                                             void* __restrict__ out,
                                             int mode, int lsh, float scale,
                                             int m0, int n0,
                                             ushort_t* As, ushort_t* Bs, int tid) {
    const int wave = tid >> 6, lane = tid & 63;
    const int quad = lane >> 4, l15 = lane & 15;
    const int wm = wave >> 1, wn = wave & 1;
    const f32x4 z4 = {0.f, 0.f, 0.f, 0.f};
    f32x4 acc[4][4];
#pragma unroll
    for (int i = 0; i < 4; ++i)
#pragma unroll
        for (int j = 0; j < 4; ++j) acc[i][j] = z4;

    const int arow = lane >> 3;        // row within 8-row chunk
    const int ablk = lane & 7;         // 16B block 0..7
    const int kswz = (ablk ^ arow) * 8;

    for (int kk = 0; kk < 768; kk += 64) {
        __syncthreads();
#pragma unroll
        for (int i = 0; i < 4; ++i) {
            int c = wave * 4 + i;      // 16 chunks of 8 rows = 128 rows
            gld16(A + (size_t)(m0 + c * 8 + arow) * 768 + kk + kswz, (void*)(As + c * 512));
            gld16(Bt + (size_t)(n0 + c * 8 + arow) * 768 + kk + kswz, (void*)(Bs + c * 512));
        }
        __syncthreads();
#pragma unroll
        for (int ks = 0; ks < 2; ++ks) {
            bf16x8 af[4], bf[4];
#pragma unroll
            for (int mb = 0; mb < 4; ++mb) {
                int r = wm * 64 + mb * 16 + l15;
                af[mb] = *(const bf16x8*)(As + r * 64 + (((ks * 4 + quad) ^ (r & 7)) * 8));
            }
#pragma unroll
            for (int nb = 0; nb < 4; ++nb) {
                int r = wn * 64 + nb * 16 + l15;
                bf[nb] = *(const bf16x8*)(Bs + r * 64 + (((ks * 4 + quad) ^ (r & 7)) * 8));
            }
#pragma unroll
            for (int mb = 0; mb < 4; ++mb)
#pragma unroll
                for (int nb = 0; nb < 4; ++nb)
                    acc[mb][nb] = __builtin_amdgcn_mfma_f32_16x16x32_bf16(af[mb], bf[nb], acc[mb][nb], 0, 0, 0);
        }
    }

#pragma unroll
    for (int mb = 0; mb < 4; ++mb) {
        int mbase = m0 + wm * 64 + mb * 16 + quad * 4;
#pragma unroll
        for (int nb = 0; nb < 4; ++nb) {
            int n = n0 + wn * 64 + nb * 16 + l15;
            gemm_store(bias, acc[mb][nb], out, mode, lsh, scale, mbase, n);
        }
    }
}

// ----------------------------------------- 64x64 GEMM body, BK=64 (out-proj)
__device__ __forceinline__ void gemm_body64(const ushort_t* __restrict__ A,
                                            const ushort_t* __restrict__ Bt,
                                            const float* __restrict__ bias,
                                            void* __restrict__ out,
                                            int mode, int lsh, float scale,
                                            int m0, int n0,
                                            ushort_t* As, ushort_t* Bs, int tid) {
    const int wave = tid >> 6, lane = tid & 63;
    const int quad = lane >> 4, l15 = lane & 15;
    const f32x4 z4 = {0.f, 0.f, 0.f, 0.f};
    f32x4 acc[4];
#pragma unroll
    for (int j = 0; j < 4; ++j) acc[j] = z4;

    const int arow = lane >> 3;
    const int ablk = lane & 7;
    const int kswz = (ablk ^ arow) * 8;

    for (int kk = 0; kk < 768; kk += 64) {
        __syncthreads();
#pragma unroll
        for (int i = 0; i < 2; ++i) {
            int c = wave * 2 + i;
            gld16(A + (size_t)(m0 + c * 8 + arow) * 768 + kk + kswz, (void*)(As + c * 512));
            gld16(Bt + (size_t)(n0 + c * 8 + arow) * 768 + kk + kswz, (void*)(Bs + c * 512));
        }
        __syncthreads();
#pragma unroll
        for (int ks = 0; ks < 2; ++ks) {
            bf16x8 af, bf[4];
            {
                int r = wave * 16 + l15;
                af = *(const bf16x8*)(As + r * 64 + (((ks * 4 + quad) ^ (r & 7)) * 8));
            }
#pragma unroll
            for (int nb = 0; nb < 4; ++nb) {
                int r = nb * 16 + l15;
                bf[nb] = *(const bf16x8*)(Bs + r * 64 + (((ks * 4 + quad) ^ (r & 7)) * 8));
            }
#pragma unroll
            for (int nb = 0; nb < 4; ++nb)
                acc[nb] = __builtin_amdgcn_mfma_f32_16x16x32_bf16(af, bf[nb], acc[nb], 0, 0, 0);
        }
    }

    int mbase = m0 + wave * 16 + quad * 4;
#pragma unroll
    for (int nb = 0; nb < 4; ++nb) {
        int n = n0 + nb * 16 + l15;
        gemm_store(bias, acc[nb], out, mode, lsh, scale, mbase, n);
    }
}

// ------------------------------------------ fused Q/K/V projections, 128x128
__global__ __launch_bounds__(256) void proj3(const ushort_t* __restrict__ qc,
                                             const ushort_t* __restrict__ kvc,
                                             const ushort_t* __restrict__ wtq,
                                             const ushort_t* __restrict__ wtk,
                                             const ushort_t* __restrict__ wtv,
                                             const float* __restrict__ bq,
                                             const float* __restrict__ bk,
                                             const float* __restrict__ bv,
                                             ushort_t* __restrict__ qp,
                                             ushort_t* __restrict__ kp,
                                             ushort_t* __restrict__ vtp) {
    __shared__ __align__(16) ushort_t As[128 * 64];
    __shared__ __align__(16) ushort_t Bs[128 * 64];
    const int bid = blockIdx.x, tid = threadIdx.x;
    if (bid < 96) {            // Q: A=wtq, B=qc(2048 rows)
        int t = bid;
        int nt = (t & 7) + 8 * ((t >> 3) & 1), mt = t >> 4;
        gemm_body128(wtq, qc, bq, qp, 3, 10, QSCALE, mt * 128, nt * 128, As, Bs, tid);
    } else if (bid < 480) {    // K: A=wtk, B=kvc(8192 rows)
        int t = bid - 96;
        int nt = (t & 7) + 8 * ((t >> 3) & 7), mt = t >> 6;
        gemm_body128(wtk, kvc, bk, kp, 3, 12, 1.0f, mt * 128, nt * 128, As, Bs, tid);
    } else {                   // V: A=kvc(8192 rows), B=wtv
        int t = bid - 480, mt = t & 63, nt = t >> 6;
        gemm_body128(kvc, wtv, bv, vtp, 2, 12, 1.0f, mt * 128, nt * 128, As, Bs, tid);
    }
}

// ------------------------------------------------------------ output GEMM
__global__ __launch_bounds__(256) void gemm_out(const ushort_t* __restrict__ ab,
                                                const ushort_t* __restrict__ wto,
                                                const float* __restrict__ bo,
                                                float* __restrict__ out) {
    __shared__ __align__(16) ushort_t As[64 * 64];
    __shared__ __align__(16) ushort_t Bs[64 * 64];
    const int bid = blockIdx.x, tid = threadIdx.x;
    int j = bid >> 3;
    int nt = (bid & 7) + 8 * (j & 3), mt = j >> 2;   // nt 0..31, mt 0..11
    gemm_body64(wto, ab, bo, out, 4, 0, 1.0f, mt * 64, nt * 64, As, Bs, tid);
}

// ---------------------- flash attention, S^T formulation, N-split x 2
// 768 blocks, XCD-pinned. Per wave: 16 q-rows. S^T = K·Q^T via operand swap
// (A/B frag lane-maps are identical) -> col=q, row=n C-layout. lsum is a
// scalar per lane; P^T packs to bf16x4 (4 ds_write_b64) and reads back as
// PV B-frags (2 ds_read_b128); O^T = V^T·P^T gives float4 po stores.
__global__ __launch_bounds__(256) void attn64s(const ushort_t* __restrict__ qp,
                                               const ushort_t* __restrict__ kp,
                                               const ushort_t* __restrict__ vt,
                                               const ushort_t* __restrict__ b1b,
                                               const ushort_t* __restrict__ wtab,
                                               float* __restrict__ po,
                                               float* __restrict__ pl) {
    __shared__ __align__(16) ushort_t k_s[64 * 64];
    __shared__ __align__(16) ushort_t v_s[64 * 64];
    __shared__ __align__(16) __bf16 pB[4][16 * 72];   // [wave][q*72 + n]

    const int tid = threadIdx.x;
    const int wave = tid >> 6, lane = tid & 63;
    const int quad = lane >> 4, l15 = lane & 15;
    const int bid = blockIdx.x;
    const int xcd = bid & 7;
    const int slot = bid >> 3;           // 0..95
    const int g = xcd + 8 * (slot >> 5); // (b,h) group 0..23, pinned to xcd
    const int member = slot & 31;        // 0..31
    const int b = g / 12, h = g - b * 12;
    const int qt = member & 15, sp = member >> 4;   // sp 0..1
    const int q0 = qt * 64;
    const int bh = g;

    const ushort_t* qg = qp + ((size_t)bh * 1024 + q0) * 64;
    const ushort_t* kg = kp + (size_t)bh * 4096 * 64;
    const ushort_t* vg = vt + (size_t)bh * 64 * 4096;

    const int rowq = wave * 16 + l15;
    // Q as B-operand (col=q=l15, k=d): same per-lane data as before
    bf16x8 aq[2];
#pragma unroll
    for (int ks = 0; ks < 2; ++ks)
        aq[ks] = *(const bf16x8*)(qg + (size_t)rowq * 64 + (ks * 4 + quad) * 8);
    // b1 as B-operand (col=q, k=rel-dim)
    bf16x8 ab1 = *(const bf16x8*)(b1b + ((size_t)(h * 1024 + q0 + rowq)) * 32 + quad * 8);

    const f32x4 mC = {NEG8L, NEG8L, NEG8L, NEG8L};
    const f32x4 z4 = {0.f, 0.f, 0.f, 0.f};
    f32x4 o[4];          // O^T: o[dt][r] = O[q=l15][d=dt*16+quad*4+r]
    float lsum = 0.f;    // row-sum for q=l15 (partial over this lane's n)
#pragma unroll
    for (int d = 0; d < 4; ++d) o[d] = z4;

    const int arow = lane >> 3;
    const int ablk = lane & 7;
    const int nbase = sp * 2048;
    __bf16* pw = &pB[wave][0];

    for (int nt = 0; nt < 32; ++nt) {
        const int n0 = nbase + nt * 64;
        __syncthreads();
#pragma unroll
        for (int i = 0; i < 2; ++i) {
            int c = wave * 2 + i;
            int row = c * 8 + arow;
            int k16 = ablk ^ (row & 7);
            gld16(kg + (size_t)(n0 + row) * 64 + k16 * 8, (void*)(k_s + c * 512));
            gld16(vg + (size_t)row * 4096 + n0 + k16 * 8, (void*)(v_s + c * 512));
        }
        // wtab as A-operand (row=n=l15, k=rel-dim); latency drains in barrier
        bf16x8 wf[4];
#pragma unroll
        for (int nb = 0; nb < 4; ++nb)
            wf[nb] = *(const bf16x8*)(wtab + (size_t)(n0 + nb * 16 + l15) * 32 + quad * 8);
        __syncthreads();

        // S^T = wtab·b1^T + K·Q^T - 8log2e   (col=q, row=n)
        f32x4 s[4];
#pragma unroll
        for (int nb = 0; nb < 4; ++nb) {
            s[nb] = __builtin_amdgcn_mfma_f32_16x16x32_bf16(wf[nb], ab1, mC, 0, 0, 0);
#pragma unroll
            for (int ks = 0; ks < 2; ++ks) {
                int rn = nb * 16 + l15;
                bf16x8 bk = *(const bf16x8*)(k_s + rn * 64 + (((ks * 4 + quad) ^ (rn & 7)) * 8));
                s[nb] = __builtin_amdgcn_mfma_f32_16x16x32_bf16(bk, aq[ks], s[nb], 0, 0, 0);
            }
        }
        // p = exp2(s); pack 4 bf16 (n-consecutive) and write P^T[q][n]
#pragma unroll
        for (int nb = 0; nb < 4; ++nb) {
            bf16x4v pv;
#pragma unroll
            for (int r = 0; r < 4; ++r) {
                float p = exp2f(s[nb][r]);
                lsum += p;
                pv[r] = (__bf16)p;
            }
            *(bf16x4v*)(pw + l15 * 72 + nb * 16 + quad * 4) = pv;
        }
        // PV: O^T += V^T · P^T  (A=v_s rows=d, B=pB col=q, k=n)
#pragma unroll
        for (int ks = 0; ks < 2; ++ks) {
            bf16x8 bp = *(const bf16x8*)(pw + l15 * 72 + ks * 32 + quad * 8);
#pragma unroll
            for (int dt = 0; dt < 4; ++dt) {
                int rd = dt * 16 + l15;
                bf16x8 av = *(const bf16x8*)(v_s + rd * 64 + (((ks * 4 + quad) ^ (rd & 7)) * 8));
                o[dt] = __builtin_amdgcn_mfma_f32_16x16x32_bf16(av, bp, o[dt], 0, 0, 0);
            }
        }
    }

    // total row sum for q=l15: reduce across the 4 quads
    lsum += __shfl_xor(lsum, 16, 64);
    lsum += __shfl_xor(lsum, 32, 64);

    const size_t pbase = ((size_t)(sp * 24 + bh)) * 1024;
    const int qrow = q0 + wave * 16 + l15;
    if (lane < 16) pl[pbase + qrow] = lsum;
#pragma unroll
    for (int dt = 0; dt < 4; ++dt)
        *(float4*)(po + (pbase + qrow) * 64 + dt * 16 + quad * 4) = (float4){o[dt][0], o[dt][1], o[dt][2], o[dt][3]};
}

// ----------------------------------------------------------- split combine
__global__ __launch_bounds__(256) void combine(const float* __restrict__ po,
                                               const float* __restrict__ pl,
                                               ushort_t* __restrict__ ab) {
    int idx = blockIdx.x * 256 + threadIdx.x;
    int e = idx * 4;
    int b = e / 786432;
    int rem = e - b * 786432;
    int q = rem / 768;
    int col = rem - q * 768;
    int h = col >> 6, d = col & 63;
    int bh = b * 12 + h;
    float4 acc = {0.f, 0.f, 0.f, 0.f};
    float l = 0.f;
#pragma unroll
    for (int s = 0; s < 2; ++s) {
        size_t base = ((size_t)(s * 24 + bh)) * 1024 + q;
        float4 v = *(const float4*)(po + base * 64 + d);
        acc.x += v.x; acc.y += v.y; acc.z += v.z; acc.w += v.w;
        l += pl[base];
    }
    float inv = 1.0f / l;
    us4 v;
    v.x = f2b(acc.x * inv); v.y = f2b(acc.y * inv);
    v.z = f2b(acc.z * inv); v.w = f2b(acc.w * inv);
    *(us4*)(ab + (size_t)(b * 1024 + q) * 768 + col) = v;
}

// ------------------------------------------------------------------- launch
extern "C" void kernel_launch(void* const* d_in, const int* in_sizes, int n_in,
                              void* d_out, int out_size, void* d_ws, size_t ws_size,
                              hipStream_t stream) {
    const float* query = (const float*)d_in[0];
    const float* keyv  = (const float*)d_in[1];
    const float* Wq = (const float*)d_in[2];
    const float* bq = (const float*)d_in[3];
    const float* Wk = (const float*)d_in[4];
    const float* bk = (const float*)d_in[5];
    const float* Wv = (const float*)d_in[6];
    const float* bv = (const float*)d_in[7];
    const float* Wo = (const float*)d_in[8];
    const float* bo = (const float*)d_in[9];
    const float* rel = (const float*)d_in[10];

    char* ws = (char*)d_ws;
    ushort_t* qc   = (ushort_t*)(ws + 0);
    ushort_t* kvc  = (ushort_t*)(ws + 3145728);
    ushort_t* wtq  = (ushort_t*)(ws + 15728640);
    ushort_t* wtk  = (ushort_t*)(ws + 16908288);
    ushort_t* wtv  = (ushort_t*)(ws + 18087936);
    ushort_t* wto  = (ushort_t*)(ws + 19267584);
    ushort_t* qp   = (ushort_t*)(ws + 20447232);  // [B,H,Q,64] bf16 (x0.125*log2e)
    ushort_t* kp   = (ushort_t*)(ws + 23592960);  // [B,H,N,64] bf16
    ushort_t* vtp  = (ushort_t*)(ws + 36175872);  // [B,H,64,N] bf16
    ushort_t* b1b  = (ushort_t*)(ws + 48758784);  // [H,Q,32] bf16 (x log2e)
    ushort_t* wtab = (ushort_t*)(ws + 49545216);  // [N,32] bf16
    ushort_t* ab   = (ushort_t*)(ws + 49807360);  // [B,Q,768] bf16
    float*    po   = (float*)(ws + 52953088);     // [2,B*H,Q,64] f32 (12.6 MB)
    float*    pl   = (float*)(ws + 65536000);     // [2,B*H,Q] f32
    // total ws usage: ~65.7 MB

    prep<<<11536, 256, 0, stream>>>(query, keyv, Wq, Wk, Wv, Wo, rel,
                                    qc, kvc, wtq, wtk, wtv, wto, b1b, wtab);
    proj3<<<864, 256, 0, stream>>>(qc, kvc, wtq, wtk, wtv, bq, bk, bv, qp, kp, vtp);
    attn64s<<<768, 256, 0, stream>>>(qp, kp, vtp, b1b, wtab, po, pl);
    combine<<<1536, 256, 0, stream>>>(po, pl, ab);
    gemm_out<<<384, 256, 0, stream>>>(ab, wto, bo, (float*)d_out);
}

// Round 11
// 204.417 us; speedup vs baseline: 1.1336x; 1.0684x over previous
//
#include <hip/hip_runtime.h>
#include <stdint.h>

// Problem constants: B=2, Q=1024, N=4096, C=768, H=12, D=64, REL=32
// Inputs/outputs fp32 (established R1/R2).
typedef unsigned short ushort_t;
typedef __bf16 bf16x8 __attribute__((ext_vector_type(8)));
typedef __bf16 bf16x4v __attribute__((ext_vector_type(4)));
typedef float f32x4 __attribute__((ext_vector_type(4)));
typedef unsigned short us4 __attribute__((ext_vector_type(4)));

#define LOG2E 1.4426950408889634f
#define NEG8L (-11.541560327111707f)   // -8*log2(e)
#define QSCALE 0.18033688011110974f    // 0.125*log2(e)

__device__ __forceinline__ ushort_t f2b(float f) {
    unsigned u = __float_as_uint(f);
    unsigned r = (u + 0x7fffu + ((u >> 16) & 1u)) >> 16;
    return (ushort_t)r;
}
__device__ __forceinline__ void gld16(const void* g, void* l) {
    __builtin_amdgcn_global_load_lds(
        (__attribute__((address_space(1))) void*)g,
        (__attribute__((address_space(3))) void*)l,
        16, 0, 0);
}

// ------------------------------------------------------------ fused prep
__global__ __launch_bounds__(256) void prep(
        const float* __restrict__ query, const float* __restrict__ keyv,
        const float* __restrict__ Wq, const float* __restrict__ Wk,
        const float* __restrict__ Wv, const float* __restrict__ Wo,
        const float* __restrict__ rel,
        ushort_t* __restrict__ qc, ushort_t* __restrict__ kvc,
        ushort_t* __restrict__ wtq, ushort_t* __restrict__ wtk,
        ushort_t* __restrict__ wtv, ushort_t* __restrict__ wto,
        ushort_t* __restrict__ b1b, ushort_t* __restrict__ wtab) {
    __shared__ ushort_t tsh[32][33];
    const int bid = blockIdx.x, tid = threadIdx.x;
    if (bid < 7680) {
        const float* src = (bid < 1536) ? query : keyv;
        ushort_t* dst = (bid < 1536) ? qc : kvc;
        int i = ((bid < 1536) ? bid : bid - 1536) * 256 + tid;
        float4 x = ((const float4*)src)[i];
        us4 v; v.x = f2b(x.x); v.y = f2b(x.y); v.z = f2b(x.z); v.w = f2b(x.w);
        ((us4*)dst)[i] = v;
    } else if (bid < 9984) {
        int t = bid - 7680, w = t / 576, tt = t - w * 576;
        const float* in = (w == 0) ? Wq : (w == 1) ? Wk : (w == 2) ? Wv : Wo;
        ushort_t* out = (w == 0) ? wtq : (w == 1) ? wtk : (w == 2) ? wtv : wto;
        int x = tid & 31, y = tid >> 5;
        int bx = (tt % 24) * 32, by = (tt / 24) * 32;
#pragma unroll
        for (int j = 0; j < 32; j += 8)
            tsh[y + j][x] = f2b(in[(size_t)(by + y + j) * 768 + bx + x]);
        __syncthreads();
#pragma unroll
        for (int j = 0; j < 32; j += 8)
            out[(size_t)(bx + y + j) * 768 + by + x] = tsh[x][y + j];
    } else if (bid < 11520) {
        int idx = (bid - 9984) * 256 + tid;
        int j = idx & 31, q = (idx >> 5) & 1023, h = idx >> 15;
        float pos = q * (31.0f / 1023.0f);
        float fl = floorf(pos);
        int lo = (int)fl; if (lo > 31) lo = 31;
        float w = pos - fl;
        int hi = lo + 1; if (hi > 31) hi = 31;
        float vlo = rel[(h * 32 + lo) * 32 + j];
        float vhi = rel[(h * 32 + hi) * 32 + j];
        b1b[idx] = f2b((vlo + (vhi - vlo) * w) * LOG2E);
    } else {
        int n = (bid - 11520) * 256 + tid;
        float pos = n * (31.0f / 4095.0f);
        float fl = floorf(pos);
        int ln = (int)fl; if (ln > 31) ln = 31;
        float wn = pos - fl;
        int hn = ln + 1; if (hn > 31) hn = 31;
        float vals[32];
#pragma unroll
        for (int j = 0; j < 32; ++j) vals[j] = 0.f;
        vals[ln] += 1.0f - wn;
        vals[hn] += wn;
#pragma unroll
        for (int j = 0; j < 32; ++j) wtab[n * 32 + j] = f2b(vals[j]);
    }
}

// ------------------------------------------------- epilogue store (shared)
// mode 2: A=activations(m), B=weights(n): V^T layout, us4 over act-rows
// mode 3: A=weights(m), B=activations(n): C^T head-split, us4 over d
// mode 4: A=weights(m), B=activations(n): fp32 float4 over out-cols
__device__ __forceinline__ void gemm_store(const float* __restrict__ bias,
                                           f32x4 a, void* out,
                                           int mode, int lsh, float scale,
                                           int mbase, int n) {
    if (mode == 2) {
        int h = n >> 6, d = n & 63;
        int b = mbase >> lsh, l = mbase & ((1 << lsh) - 1);
        float bvf = bias[n];
        us4 v;
        v.x = f2b((a[0] + bvf) * scale);
        v.y = f2b((a[1] + bvf) * scale);
        v.z = f2b((a[2] + bvf) * scale);
        v.w = f2b((a[3] + bvf) * scale);
        *(us4*)((ushort_t*)out + ((size_t)((b * 12 + h) * 64 + d) << lsh) + l) = v;
    } else if (mode == 3) {
        int h = mbase >> 6, dbase = mbase & 63;
        int b = n >> lsh, l = n & ((1 << lsh) - 1);
        us4 v;
        v.x = f2b((a[0] + bias[mbase + 0]) * scale);
        v.y = f2b((a[1] + bias[mbase + 1]) * scale);
        v.z = f2b((a[2] + bias[mbase + 2]) * scale);
        v.w = f2b((a[3] + bias[mbase + 3]) * scale);
        *(us4*)((ushort_t*)out + ((((size_t)(b * 12 + h) << lsh) + l) << 6) + dbase) = v;
    } else {  // mode 4
        float4 v;
        v.x = (a[0] + bias[mbase + 0]) * scale;
        v.y = (a[1] + bias[mbase + 1]) * scale;
        v.z = (a[2] + bias[mbase + 2]) * scale;
        v.w = (a[3] + bias[mbase + 3]) * scale;
        *(float4*)((float*)out + (size_t)n * 768 + mbase) = v;
    }
}

// --------------------------------------- 128x128 GEMM body, BK=128 (K=768)
// 6 rounds, 12 barriers. Staging: 4-row chunks of 256B rows, XOR-16 block
// swizzle; fragment reads are b128, 2-way max on banks.
__device__ __forceinline__ void gemm_body128(const ushort_t* __restrict__ A,
                                             const ushort_t* __restrict__ Bt,
                                             const float* __restrict__ bias,
                                             void* __restrict__ out,
                                             int mode, int lsh, float scale,
                                             int m0, int n0,
                                             ushort_t* As, ushort_t* Bs, int tid) {
    const int wave = tid >> 6, lane = tid & 63;
    const int quad = lane >> 4, l15 = lane & 15;
    const int wm = wave >> 1, wn = wave & 1;
    const f32x4 z4 = {0.f, 0.f, 0.f, 0.f};
    f32x4 acc[4][4];
#pragma unroll
    for (int i = 0; i < 4; ++i)
#pragma unroll
        for (int j = 0; j < 4; ++j) acc[i][j] = z4;

    const int arow4 = lane >> 4;       // row within 4-row chunk
    const int ablk16 = lane & 15;      // 16B block 0..15 (256B row)

    for (int kk = 0; kk < 768; kk += 128) {
        __syncthreads();
#pragma unroll
        for (int i = 0; i < 8; ++i) {
            int c = wave * 8 + i;      // 32 chunks of 4 rows = 128 rows
            int row = c * 4 + arow4;
            int swz = (ablk16 ^ (row & 15)) * 8;
            gld16(A + (size_t)(m0 + row) * 768 + kk + swz, (void*)(As + c * 512));
            gld16(Bt + (size_t)(n0 + row) * 768 + kk + swz, (void*)(Bs + c * 512));
        }
        __syncthreads();
#pragma unroll
        for (int ks = 0; ks < 4; ++ks) {
            bf16x8 af[4], bf[4];
#pragma unroll
            for (int mb = 0; mb < 4; ++mb) {
                int r = wm * 64 + mb * 16 + l15;
                af[mb] = *(const bf16x8*)(As + r * 128 + (((ks * 4 + quad) ^ (r & 15)) * 8));
            }
#pragma unroll
            for (int nb = 0; nb < 4; ++nb) {
                int r = wn * 64 + nb * 16 + l15;
                bf[nb] = *(const bf16x8*)(Bs + r * 128 + (((ks * 4 + quad) ^ (r & 15)) * 8));
            }
#pragma unroll
            for (int mb = 0; mb < 4; ++mb)
#pragma unroll
                for (int nb = 0; nb < 4; ++nb)
                    acc[mb][nb] = __builtin_amdgcn_mfma_f32_16x16x32_bf16(af[mb], bf[nb], acc[mb][nb], 0, 0, 0);
        }
    }

#pragma unroll
    for (int mb = 0; mb < 4; ++mb) {
        int mbase = m0 + wm * 64 + mb * 16 + quad * 4;
#pragma unroll
        for (int nb = 0; nb < 4; ++nb) {
            int n = n0 + wn * 64 + nb * 16 + l15;
            gemm_store(bias, acc[mb][nb], out, mode, lsh, scale, mbase, n);
        }
    }
}

// ----------------------------------------- 64x64 GEMM body, BK=64 (out-proj)
__device__ __forceinline__ void gemm_body64(const ushort_t* __restrict__ A,
                                            const ushort_t* __restrict__ Bt,
                                            const float* __restrict__ bias,
                                            void* __restrict__ out,
                                            int mode, int lsh, float scale,
                                            int m0, int n0,
                                            ushort_t* As, ushort_t* Bs, int tid) {
    const int wave = tid >> 6, lane = tid & 63;
    const int quad = lane >> 4, l15 = lane & 15;
    const f32x4 z4 = {0.f, 0.f, 0.f, 0.f};
    f32x4 acc[4];
#pragma unroll
    for (int j = 0; j < 4; ++j) acc[j] = z4;

    const int arow = lane >> 3;
    const int ablk = lane & 7;
    const int kswz = (ablk ^ arow) * 8;

    for (int kk = 0; kk < 768; kk += 64) {
        __syncthreads();
#pragma unroll
        for (int i = 0; i < 2; ++i) {
            int c = wave * 2 + i;
            gld16(A + (size_t)(m0 + c * 8 + arow) * 768 + kk + kswz, (void*)(As + c * 512));
            gld16(Bt + (size_t)(n0 + c * 8 + arow) * 768 + kk + kswz, (void*)(Bs + c * 512));
        }
        __syncthreads();
#pragma unroll
        for (int ks = 0; ks < 2; ++ks) {
            bf16x8 af, bf[4];
            {
                int r = wave * 16 + l15;
                af = *(const bf16x8*)(As + r * 64 + (((ks * 4 + quad) ^ (r & 7)) * 8));
            }
#pragma unroll
            for (int nb = 0; nb < 4; ++nb) {
                int r = nb * 16 + l15;
                bf[nb] = *(const bf16x8*)(Bs + r * 64 + (((ks * 4 + quad) ^ (r & 7)) * 8));
            }
#pragma unroll
            for (int nb = 0; nb < 4; ++nb)
                acc[nb] = __builtin_amdgcn_mfma_f32_16x16x32_bf16(af, bf[nb], acc[nb], 0, 0, 0);
        }
    }

    int mbase = m0 + wave * 16 + quad * 4;
#pragma unroll
    for (int nb = 0; nb < 4; ++nb) {
        int n = n0 + nb * 16 + l15;
        gemm_store(bias, acc[nb], out, mode, lsh, scale, mbase, n);
    }
}

// ------------------------------------------ fused Q/K/V projections, 128x128
__global__ __launch_bounds__(256) void proj3(const ushort_t* __restrict__ qc,
                                             const ushort_t* __restrict__ kvc,
                                             const ushort_t* __restrict__ wtq,
                                             const ushort_t* __restrict__ wtk,
                                             const ushort_t* __restrict__ wtv,
                                             const float* __restrict__ bq,
                                             const float* __restrict__ bk,
                                             const float* __restrict__ bv,
                                             ushort_t* __restrict__ qp,
                                             ushort_t* __restrict__ kp,
                                             ushort_t* __restrict__ vtp) {
    __shared__ __align__(16) ushort_t As[128 * 128];
    __shared__ __align__(16) ushort_t Bs[128 * 128];
    const int bid = blockIdx.x, tid = threadIdx.x;
    if (bid < 96) {            // Q: A=wtq, B=qc(2048 rows)
        int t = bid;
        int nt = (t & 7) + 8 * ((t >> 3) & 1), mt = t >> 4;
        gemm_body128(wtq, qc, bq, qp, 3, 10, QSCALE, mt * 128, nt * 128, As, Bs, tid);
    } else if (bid < 480) {    // K: A=wtk, B=kvc(8192 rows)
        int t = bid - 96;
        int nt = (t & 7) + 8 * ((t >> 3) & 7), mt = t >> 6;
        gemm_body128(wtk, kvc, bk, kp, 3, 12, 1.0f, mt * 128, nt * 128, As, Bs, tid);
    } else {                   // V: A=kvc(8192 rows), B=wtv
        int t = bid - 480, mt = t & 63, nt = t >> 6;
        gemm_body128(kvc, wtv, bv, vtp, 2, 12, 1.0f, mt * 128, nt * 128, As, Bs, tid);
    }
}

// ------------------------------------------------------------ output GEMM
__global__ __launch_bounds__(256) void gemm_out(const ushort_t* __restrict__ ab,
                                                const ushort_t* __restrict__ wto,
                                                const float* __restrict__ bo,
                                                float* __restrict__ out) {
    __shared__ __align__(16) ushort_t As[64 * 64];
    __shared__ __align__(16) ushort_t Bs[64 * 64];
    const int bid = blockIdx.x, tid = threadIdx.x;
    int j = bid >> 3;
    int nt = (bid & 7) + 8 * (j & 3), mt = j >> 2;   // nt 0..31, mt 0..11
    gemm_body64(wto, ab, bo, out, 4, 0, 1.0f, mt * 64, nt * 64, As, Bs, tid);
}

// ------------- flash attention, S^T form, 128-n rounds (16 rounds/block)
// 768 blocks, XCD-pinned. k_s: 128 n-rows x 64 d (8-row chunks, XOR-8);
// v_s: 64 d-rows x 128 n (4-row chunks, XOR-16). pB stride 136 (16B-aligned).
__global__ __launch_bounds__(256) void attn64s(const ushort_t* __restrict__ qp,
                                               const ushort_t* __restrict__ kp,
                                               const ushort_t* __restrict__ vt,
                                               const ushort_t* __restrict__ b1b,
                                               const ushort_t* __restrict__ wtab,
                                               float* __restrict__ po,
                                               float* __restrict__ pl) {
    __shared__ __align__(16) ushort_t k_s[128 * 64];
    __shared__ __align__(16) ushort_t v_s[64 * 128];
    __shared__ __align__(16) __bf16 pB[4][16 * 136];   // [wave][q*136 + n]

    const int tid = threadIdx.x;
    const int wave = tid >> 6, lane = tid & 63;
    const int quad = lane >> 4, l15 = lane & 15;
    const int bid = blockIdx.x;
    const int xcd = bid & 7;
    const int slot = bid >> 3;           // 0..95
    const int g = xcd + 8 * (slot >> 5); // (b,h) group 0..23, pinned to xcd
    const int member = slot & 31;        // 0..31
    const int b = g / 12, h = g - b * 12;
    const int qt = member & 15, sp = member >> 4;   // sp 0..1
    const int q0 = qt * 64;
    const int bh = g;

    const ushort_t* qg = qp + ((size_t)bh * 1024 + q0) * 64;
    const ushort_t* kg = kp + (size_t)bh * 4096 * 64;
    const ushort_t* vg = vt + (size_t)bh * 64 * 4096;

    const int rowq = wave * 16 + l15;
    bf16x8 aq[2];
#pragma unroll
    for (int ks = 0; ks < 2; ++ks)
        aq[ks] = *(const bf16x8*)(qg + (size_t)rowq * 64 + (ks * 4 + quad) * 8);
    bf16x8 ab1 = *(const bf16x8*)(b1b + ((size_t)(h * 1024 + q0 + rowq)) * 32 + quad * 8);

    const f32x4 mC = {NEG8L, NEG8L, NEG8L, NEG8L};
    const f32x4 z4 = {0.f, 0.f, 0.f, 0.f};
    f32x4 o[4];          // O^T: o[dt][r] = O[q=l15][d=dt*16+quad*4+r]
    float lsum = 0.f;
#pragma unroll
    for (int d = 0; d < 4; ++d) o[d] = z4;

    const int arow = lane >> 3;     // k staging: row within 8-row chunk
    const int ablk = lane & 7;
    const int arow4 = lane >> 4;    // v staging: row within 4-row chunk
    const int ablk16 = lane & 15;
    const int nbase = sp * 2048;
    __bf16* pw = &pB[wave][0];

    for (int nt = 0; nt < 16; ++nt) {
        const int n0 = nbase + nt * 128;
        __syncthreads();
#pragma unroll
        for (int i = 0; i < 4; ++i) {
            int c = wave * 4 + i;
            // k: 16 chunks of 8 n-rows x 64 d
            int krow = c * 8 + arow;
            gld16(kg + (size_t)(n0 + krow) * 64 + (ablk ^ (krow & 7)) * 8,
                  (void*)(k_s + c * 512));
            // v: 16 chunks of 4 d-rows x 128 n
            int vrow = c * 4 + arow4;
            gld16(vg + (size_t)vrow * 4096 + n0 + (ablk16 ^ (vrow & 15)) * 8,
                  (void*)(v_s + c * 512));
        }
        // wtab as A-operand (row=n, k=rel-dim); latency drains in barrier
        bf16x8 wf[8];
#pragma unroll
        for (int nb = 0; nb < 8; ++nb)
            wf[nb] = *(const bf16x8*)(wtab + (size_t)(n0 + nb * 16 + l15) * 32 + quad * 8);
        __syncthreads();

        // S^T = wtab·b1^T + K·Q^T - 8log2e   (col=q, row=n), 8 nb chains
        f32x4 s[8];
#pragma unroll
        for (int nb = 0; nb < 8; ++nb) {
            s[nb] = __builtin_amdgcn_mfma_f32_16x16x32_bf16(wf[nb], ab1, mC, 0, 0, 0);
            int rn = nb * 16 + l15;
#pragma unroll
            for (int ks = 0; ks < 2; ++ks) {
                bf16x8 bk = *(const bf16x8*)(k_s + rn * 64 + (((ks * 4 + quad) ^ (rn & 7)) * 8));
                s[nb] = __builtin_amdgcn_mfma_f32_16x16x32_bf16(bk, aq[ks], s[nb], 0, 0, 0);
            }
        }
        // p = exp2(s); pack 4 bf16 (n-consecutive) and write P^T[q][n]
#pragma unroll
        for (int nb = 0; nb < 8; ++nb) {
            bf16x4v pv;
#pragma unroll
            for (int r = 0; r < 4; ++r) {
                float p = exp2f(s[nb][r]);
                lsum += p;
                pv[r] = (__bf16)p;
            }
            *(bf16x4v*)(pw + l15 * 136 + nb * 16 + quad * 4) = pv;
        }
        // PV: O^T += V^T · P^T  (A=v_s rows=d, B=pB col=q, k=n 0..127)
#pragma unroll
        for (int ks = 0; ks < 4; ++ks) {
            bf16x8 bp = *(const bf16x8*)(pw + l15 * 136 + ks * 32 + quad * 8);
#pragma unroll
            for (int dt = 0; dt < 4; ++dt) {
                int rd = dt * 16 + l15;
                bf16x8 av = *(const bf16x8*)(v_s + rd * 128 + (((ks * 4 + quad) ^ (rd & 15)) * 8));
                o[dt] = __builtin_amdgcn_mfma_f32_16x16x32_bf16(av, bp, o[dt], 0, 0, 0);
            }
        }
    }

    // total row sum for q=l15: reduce across the 4 quads
    lsum += __shfl_xor(lsum, 16, 64);
    lsum += __shfl_xor(lsum, 32, 64);

    const size_t pbase = ((size_t)(sp * 24 + bh)) * 1024;
    const int qrow = q0 + wave * 16 + l15;
    if (lane < 16) pl[pbase + qrow] = lsum;
#pragma unroll
    for (int dt = 0; dt < 4; ++dt)
        *(float4*)(po + (pbase + qrow) * 64 + dt * 16 + quad * 4) = (float4){o[dt][0], o[dt][1], o[dt][2], o[dt][3]};
}

// ----------------------------------------------------------- split combine
__global__ __launch_bounds__(256) void combine(const float* __restrict__ po,
                                               const float* __restrict__ pl,
                                               ushort_t* __restrict__ ab) {
    int idx = blockIdx.x * 256 + threadIdx.x;
    int e = idx * 4;
    int b = e / 786432;
    int rem = e - b * 786432;
    int q = rem / 768;
    int col = rem - q * 768;
    int h = col >> 6, d = col & 63;
    int bh = b * 12 + h;
    float4 acc = {0.f, 0.f, 0.f, 0.f};
    float l = 0.f;
#pragma unroll
    for (int s = 0; s < 2; ++s) {
        size_t base = ((size_t)(s * 24 + bh)) * 1024 + q;
        float4 v = *(const float4*)(po + base * 64 + d);
        acc.x += v.x; acc.y += v.y; acc.z += v.z; acc.w += v.w;
        l += pl[base];
    }
    float inv = 1.0f / l;
    us4 v;
    v.x = f2b(acc.x * inv); v.y = f2b(acc.y * inv);
    v.z = f2b(acc.z * inv); v.w = f2b(acc.w * inv);
    *(us4*)(ab + (size_t)(b * 1024 + q) * 768 + col) = v;
}

// ------------------------------------------------------------------- launch
extern "C" void kernel_launch(void* const* d_in, const int* in_sizes, int n_in,
                              void* d_out, int out_size, void* d_ws, size_t ws_size,
                              hipStream_t stream) {
    const float* query = (const float*)d_in[0];
    const float* keyv  = (const float*)d_in[1];
    const float* Wq = (const float*)d_in[2];
    const float* bq = (const float*)d_in[3];
    const float* Wk = (const float*)d_in[4];
    const float* bk = (const float*)d_in[5];
    const float* Wv = (const float*)d_in[6];
    const float* bv = (const float*)d_in[7];
    const float* Wo = (const float*)d_in[8];
    const float* bo = (const float*)d_in[9];
    const float* rel = (const float*)d_in[10];

    char* ws = (char*)d_ws;
    ushort_t* qc   = (ushort_t*)(ws + 0);
    ushort_t* kvc  = (ushort_t*)(ws + 3145728);
    ushort_t* wtq  = (ushort_t*)(ws + 15728640);
    ushort_t* wtk  = (ushort_t*)(ws + 16908288);
    ushort_t* wtv  = (ushort_t*)(ws + 18087936);
    ushort_t* wto  = (ushort_t*)(ws + 19267584);
    ushort_t* qp   = (ushort_t*)(ws + 20447232);  // [B,H,Q,64] bf16 (x0.125*log2e)
    ushort_t* kp   = (ushort_t*)(ws + 23592960);  // [B,H,N,64] bf16
    ushort_t* vtp  = (ushort_t*)(ws + 36175872);  // [B,H,64,N] bf16
    ushort_t* b1b  = (ushort_t*)(ws + 48758784);  // [H,Q,32] bf16 (x log2e)
    ushort_t* wtab = (ushort_t*)(ws + 49545216);  // [N,32] bf16
    ushort_t* ab   = (ushort_t*)(ws + 49807360);  // [B,Q,768] bf16
    float*    po   = (float*)(ws + 52953088);     // [2,B*H,Q,64] f32 (12.6 MB)
    float*    pl   = (float*)(ws + 65536000);     // [2,B*H,Q] f32
    // total ws usage: ~65.7 MB

    prep<<<11536, 256, 0, stream>>>(query, keyv, Wq, Wk, Wv, Wo, rel,
                                    qc, kvc, wtq, wtk, wtv, wto, b1b, wtab);
    proj3<<<864, 256, 0, stream>>>(qc, kvc, wtq, wtk, wtv, bq, bk, bv, qp, kp, vtp);
    attn64s<<<768, 256, 0, stream>>>(qp, kp, vtp, b1b, wtab, po, pl);
    combine<<<1536, 256, 0, stream>>>(po, pl, ab);
    gemm_out<<<384, 256, 0, stream>>>(ab, wto, bo, (float*)d_out);
}

// Round 12
// 202.984 us; speedup vs baseline: 1.1416x; 1.0071x over previous
//
#include <hip/hip_runtime.h>
#include <stdint.h>

// Problem constants: B=2, Q=1024, N=4096, C=768, H=12, D=64, REL=32
// Inputs/outputs fp32 (established R1/R2).
typedef unsigned short ushort_t;
typedef __bf16 bf16x8 __attribute__((ext_vector_type(8)));
typedef float f32x4 __attribute__((ext_vector_type(4)));
typedef unsigned short us4 __attribute__((ext_vector_type(4)));

#define LOG2E 1.4426950408889634f
#define NEG8L (-11.541560327111707f)   // -8*log2(e)
#define QSCALE 0.18033688011110974f    // 0.125*log2(e)

__device__ __forceinline__ ushort_t f2b(float f) {
    unsigned u = __float_as_uint(f);
    unsigned r = (u + 0x7fffu + ((u >> 16) & 1u)) >> 16;
    return (ushort_t)r;
}
// packed f32->bf16 (RNE). HW v_cvt_pk_bf16_f32 when available.
__device__ __forceinline__ unsigned pk2(float a, float b) {
#if __has_builtin(__builtin_amdgcn_cvt_pk_bf16_f32)
    auto v = __builtin_amdgcn_cvt_pk_bf16_f32(a, b);
    return __builtin_bit_cast(unsigned, v);
#else
    unsigned ua = __float_as_uint(a), ub = __float_as_uint(b);
    unsigned ra = (ua + 0x7fffu + ((ua >> 16) & 1u)) >> 16;
    unsigned rb = (ub + 0x7fffu + ((ub >> 16) & 1u)) >> 16;
    return ra | (rb << 16);
#endif
}
__device__ __forceinline__ us4 pk4(float a, float b, float c, float d) {
    union { unsigned u[2]; us4 v; } x;
    x.u[0] = pk2(a, b); x.u[1] = pk2(c, d);
    return x.v;
}
__device__ __forceinline__ float fexp2(float x) {
#if __has_builtin(__builtin_amdgcn_exp2f)
    return __builtin_amdgcn_exp2f(x);
#else
    return exp2f(x);
#endif
}
__device__ __forceinline__ void gld16(const void* g, void* l) {
    __builtin_amdgcn_global_load_lds(
        (__attribute__((address_space(1))) void*)g,
        (__attribute__((address_space(3))) void*)l,
        16, 0, 0);
}

// ------------------------------------------------------------ fused prep
__global__ __launch_bounds__(256) void prep(
        const float* __restrict__ query, const float* __restrict__ keyv,
        const float* __restrict__ Wq, const float* __restrict__ Wk,
        const float* __restrict__ Wv, const float* __restrict__ Wo,
        const float* __restrict__ rel,
        ushort_t* __restrict__ qc, ushort_t* __restrict__ kvc,
        ushort_t* __restrict__ wtq, ushort_t* __restrict__ wtk,
        ushort_t* __restrict__ wtv, ushort_t* __restrict__ wto,
        ushort_t* __restrict__ b1b, ushort_t* __restrict__ wtab) {
    __shared__ ushort_t tsh[32][33];
    const int bid = blockIdx.x, tid = threadIdx.x;
    if (bid < 7680) {
        const float* src = (bid < 1536) ? query : keyv;
        ushort_t* dst = (bid < 1536) ? qc : kvc;
        int i = ((bid < 1536) ? bid : bid - 1536) * 256 + tid;
        float4 x = ((const float4*)src)[i];
        ((us4*)dst)[i] = pk4(x.x, x.y, x.z, x.w);
    } else if (bid < 9984) {
        int t = bid - 7680, w = t / 576, tt = t - w * 576;
        const float* in = (w == 0) ? Wq : (w == 1) ? Wk : (w == 2) ? Wv : Wo;
        ushort_t* out = (w == 0) ? wtq : (w == 1) ? wtk : (w == 2) ? wtv : wto;
        int x = tid & 31, y = tid >> 5;
        int bx = (tt % 24) * 32, by = (tt / 24) * 32;
#pragma unroll
        for (int j = 0; j < 32; j += 8)
            tsh[y + j][x] = f2b(in[(size_t)(by + y + j) * 768 + bx + x]);
        __syncthreads();
#pragma unroll
        for (int j = 0; j < 32; j += 8)
            out[(size_t)(bx + y + j) * 768 + by + x] = tsh[x][y + j];
    } else if (bid < 11520) {
        int idx = (bid - 9984) * 256 + tid;
        int j = idx & 31, q = (idx >> 5) & 1023, h = idx >> 15;
        float pos = q * (31.0f / 1023.0f);
        float fl = floorf(pos);
        int lo = (int)fl; if (lo > 31) lo = 31;
        float w = pos - fl;
        int hi = lo + 1; if (hi > 31) hi = 31;
        float vlo = rel[(h * 32 + lo) * 32 + j];
        float vhi = rel[(h * 32 + hi) * 32 + j];
        b1b[idx] = f2b((vlo + (vhi - vlo) * w) * LOG2E);
    } else {
        int n = (bid - 11520) * 256 + tid;
        float pos = n * (31.0f / 4095.0f);
        float fl = floorf(pos);
        int ln = (int)fl; if (ln > 31) ln = 31;
        float wn = pos - fl;
        int hn = ln + 1; if (hn > 31) hn = 31;
        float vals[32];
#pragma unroll
        for (int j = 0; j < 32; ++j) vals[j] = 0.f;
        vals[ln] += 1.0f - wn;
        vals[hn] += wn;
#pragma unroll
        for (int j = 0; j < 32; ++j) wtab[n * 32 + j] = f2b(vals[j]);
    }
}

// ------------------------------------------------- epilogue store (shared)
// mode 2: A=activations(m), B=weights(n): V^T layout, us4 over act-rows
// mode 3: A=weights(m), B=activations(n): C^T head-split, us4 over d
// mode 4: A=weights(m), B=activations(n): fp32 float4 over out-cols
__device__ __forceinline__ void gemm_store(const float* __restrict__ bias,
                                           f32x4 a, void* out,
                                           int mode, int lsh, float scale,
                                           int mbase, int n) {
    if (mode == 2) {
        int h = n >> 6, d = n & 63;
        int b = mbase >> lsh, l = mbase & ((1 << lsh) - 1);
        float bvf = bias[n];
        *(us4*)((ushort_t*)out + ((size_t)((b * 12 + h) * 64 + d) << lsh) + l) =
            pk4((a[0] + bvf) * scale, (a[1] + bvf) * scale,
                (a[2] + bvf) * scale, (a[3] + bvf) * scale);
    } else if (mode == 3) {
        int h = mbase >> 6, dbase = mbase & 63;
        int b = n >> lsh, l = n & ((1 << lsh) - 1);
        *(us4*)((ushort_t*)out + ((((size_t)(b * 12 + h) << lsh) + l) << 6) + dbase) =
            pk4((a[0] + bias[mbase + 0]) * scale, (a[1] + bias[mbase + 1]) * scale,
                (a[2] + bias[mbase + 2]) * scale, (a[3] + bias[mbase + 3]) * scale);
    } else {  // mode 4
        float4 v;
        v.x = (a[0] + bias[mbase + 0]) * scale;
        v.y = (a[1] + bias[mbase + 1]) * scale;
        v.z = (a[2] + bias[mbase + 2]) * scale;
        v.w = (a[3] + bias[mbase + 3]) * scale;
        *(float4*)((float*)out + (size_t)n * 768 + mbase) = v;
    }
}

// --------------------------------------- 128x128 GEMM body, BK=128 (K=768)
__device__ __forceinline__ void gemm_body128(const ushort_t* __restrict__ A,
                                             const ushort_t* __restrict__ Bt,
                                             const float* __restrict__ bias,
                                             void* __restrict__ out,
                                             int mode, int lsh, float scale,
                                             int m0, int n0,
                                             ushort_t* As, ushort_t* Bs, int tid) {
    const int wave = tid >> 6, lane = tid & 63;
    const int quad = lane >> 4, l15 = lane & 15;
    const int wm = wave >> 1, wn = wave & 1;
    const f32x4 z4 = {0.f, 0.f, 0.f, 0.f};
    f32x4 acc[4][4];
#pragma unroll
    for (int i = 0; i < 4; ++i)
#pragma unroll
        for (int j = 0; j < 4; ++j) acc[i][j] = z4;

    const int arow4 = lane >> 4;       // row within 4-row chunk
    const int ablk16 = lane & 15;      // 16B block 0..15 (256B row)

    for (int kk = 0; kk < 768; kk += 128) {
        __syncthreads();
#pragma unroll
        for (int i = 0; i < 8; ++i) {
            int c = wave * 8 + i;      // 32 chunks of 4 rows = 128 rows
            int row = c * 4 + arow4;
            int swz = (ablk16 ^ (row & 15)) * 8;
            gld16(A + (size_t)(m0 + row) * 768 + kk + swz, (void*)(As + c * 512));
            gld16(Bt + (size_t)(n0 + row) * 768 + kk + swz, (void*)(Bs + c * 512));
        }
        __syncthreads();
#pragma unroll
        for (int ks = 0; ks < 4; ++ks) {
            bf16x8 af[4], bf[4];
#pragma unroll
            for (int mb = 0; mb < 4; ++mb) {
                int r = wm * 64 + mb * 16 + l15;
                af[mb] = *(const bf16x8*)(As + r * 128 + (((ks * 4 + quad) ^ (r & 15)) * 8));
            }
#pragma unroll
            for (int nb = 0; nb < 4; ++nb) {
                int r = wn * 64 + nb * 16 + l15;
                bf[nb] = *(const bf16x8*)(Bs + r * 128 + (((ks * 4 + quad) ^ (r & 15)) * 8));
            }
#pragma unroll
            for (int mb = 0; mb < 4; ++mb)
#pragma unroll
                for (int nb = 0; nb < 4; ++nb)
                    acc[mb][nb] = __builtin_amdgcn_mfma_f32_16x16x32_bf16(af[mb], bf[nb], acc[mb][nb], 0, 0, 0);
        }
    }

#pragma unroll
    for (int mb = 0; mb < 4; ++mb) {
        int mbase = m0 + wm * 64 + mb * 16 + quad * 4;
#pragma unroll
        for (int nb = 0; nb < 4; ++nb) {
            int n = n0 + wn * 64 + nb * 16 + l15;
            gemm_store(bias, acc[mb][nb], out, mode, lsh, scale, mbase, n);
        }
    }
}

// ----------------------------------- 64x64 GEMM body, BK=128 (out-proj)
__device__ __forceinline__ void gemm_body64(const ushort_t* __restrict__ A,
                                            const ushort_t* __restrict__ Bt,
                                            const float* __restrict__ bias,
                                            void* __restrict__ out,
                                            int mode, int lsh, float scale,
                                            int m0, int n0,
                                            ushort_t* As, ushort_t* Bs, int tid) {
    const int wave = tid >> 6, lane = tid & 63;
    const int quad = lane >> 4, l15 = lane & 15;
    const f32x4 z4 = {0.f, 0.f, 0.f, 0.f};
    f32x4 acc[4];
#pragma unroll
    for (int j = 0; j < 4; ++j) acc[j] = z4;

    const int arow4 = lane >> 4;
    const int ablk16 = lane & 15;

    for (int kk = 0; kk < 768; kk += 128) {
        __syncthreads();
#pragma unroll
        for (int i = 0; i < 4; ++i) {
            int c = wave * 4 + i;      // 16 chunks of 4 rows = 64 rows
            int row = c * 4 + arow4;
            int swz = (ablk16 ^ (row & 15)) * 8;
            gld16(A + (size_t)(m0 + row) * 768 + kk + swz, (void*)(As + c * 512));
            gld16(Bt + (size_t)(n0 + row) * 768 + kk + swz, (void*)(Bs + c * 512));
        }
        __syncthreads();
#pragma unroll
        for (int ks = 0; ks < 4; ++ks) {
            bf16x8 af, bf[4];
            {
                int r = wave * 16 + l15;
                af = *(const bf16x8*)(As + r * 128 + (((ks * 4 + quad) ^ (r & 15)) * 8));
            }
#pragma unroll
            for (int nb = 0; nb < 4; ++nb) {
                int r = nb * 16 + l15;
                bf[nb] = *(const bf16x8*)(Bs + r * 128 + (((ks * 4 + quad) ^ (r & 15)) * 8));
            }
#pragma unroll
            for (int nb = 0; nb < 4; ++nb)
                acc[nb] = __builtin_amdgcn_mfma_f32_16x16x32_bf16(af, bf[nb], acc[nb], 0, 0, 0);
        }
    }

    int mbase = m0 + wave * 16 + quad * 4;
#pragma unroll
    for (int nb = 0; nb < 4; ++nb) {
        int n = n0 + nb * 16 + l15;
        gemm_store(bias, acc[nb], out, mode, lsh, scale, mbase, n);
    }
}

// ------------------------------------------ fused Q/K/V projections, 128x128
__global__ __launch_bounds__(256) void proj3(const ushort_t* __restrict__ qc,
                                             const ushort_t* __restrict__ kvc,
                                             const ushort_t* __restrict__ wtq,
                                             const ushort_t* __restrict__ wtk,
                                             const ushort_t* __restrict__ wtv,
                                             const float* __restrict__ bq,
                                             const float* __restrict__ bk,
                                             const float* __restrict__ bv,
                                             ushort_t* __restrict__ qp,
                                             ushort_t* __restrict__ kp,
                                             ushort_t* __restrict__ vtp) {
    __shared__ __align__(16) ushort_t As[128 * 128];
    __shared__ __align__(16) ushort_t Bs[128 * 128];
    const int bid = blockIdx.x, tid = threadIdx.x;
    if (bid < 96) {            // Q: A=wtq, B=qc(2048 rows)
        int t = bid;
        int nt = (t & 7) + 8 * ((t >> 3) & 1), mt = t >> 4;
        gemm_body128(wtq, qc, bq, qp, 3, 10, QSCALE, mt * 128, nt * 128, As, Bs, tid);
    } else if (bid < 480) {    // K: A=wtk, B=kvc(8192 rows)
        int t = bid - 96;
        int nt = (t & 7) + 8 * ((t >> 3) & 7), mt = t >> 6;
        gemm_body128(wtk, kvc, bk, kp, 3, 12, 1.0f, mt * 128, nt * 128, As, Bs, tid);
    } else {                   // V: A=kvc(8192 rows), B=wtv
        int t = bid - 480, mt = t & 63, nt = t >> 6;
        gemm_body128(kvc, wtv, bv, vtp, 2, 12, 1.0f, mt * 128, nt * 128, As, Bs, tid);
    }
}

// ------------------------------------------------------------ output GEMM
__global__ __launch_bounds__(256) void gemm_out(const ushort_t* __restrict__ ab,
                                                const ushort_t* __restrict__ wto,
                                                const float* __restrict__ bo,
                                                float* __restrict__ out) {
    __shared__ __align__(16) ushort_t As[64 * 128];
    __shared__ __align__(16) ushort_t Bs[64 * 128];
    const int bid = blockIdx.x, tid = threadIdx.x;
    int j = bid >> 3;
    int nt = (bid & 7) + 8 * (j & 3), mt = j >> 2;   // nt 0..31, mt 0..11
    gemm_body64(wto, ab, bo, out, 4, 0, 1.0f, mt * 64, nt * 64, As, Bs, tid);
}

// ------------- flash attention, S^T form, 128-n rounds (16 rounds/block)
// 768 blocks, XCD-pinned. Row sums via ones-vector MFMA against the PV
// B-fragments (replaces per-lane adds + shuffles); P packed with pk-cvt.
__global__ __launch_bounds__(256) void attn64s(const ushort_t* __restrict__ qp,
                                               const ushort_t* __restrict__ kp,
                                               const ushort_t* __restrict__ vt,
                                               const ushort_t* __restrict__ b1b,
                                               const ushort_t* __restrict__ wtab,
                                               float* __restrict__ po,
                                               float* __restrict__ pl) {
    __shared__ __align__(16) ushort_t k_s[128 * 64];
    __shared__ __align__(16) ushort_t v_s[64 * 128];
    __shared__ __align__(16) ushort_t pB[4][16 * 136];   // [wave][q*136 + n]

    const int tid = threadIdx.x;
    const int wave = tid >> 6, lane = tid & 63;
    const int quad = lane >> 4, l15 = lane & 15;
    const int bid = blockIdx.x;
    const int xcd = bid & 7;
    const int slot = bid >> 3;           // 0..95
    const int g = xcd + 8 * (slot >> 5); // (b,h) group 0..23, pinned to xcd
    const int member = slot & 31;        // 0..31
    const int b = g / 12, h = g - b * 12;
    const int qt = member & 15, sp = member >> 4;   // sp 0..1
    const int q0 = qt * 64;
    const int bh = g;

    const ushort_t* qg = qp + ((size_t)bh * 1024 + q0) * 64;
    const ushort_t* kg = kp + (size_t)bh * 4096 * 64;
    const ushort_t* vg = vt + (size_t)bh * 64 * 4096;

    const int rowq = wave * 16 + l15;
    bf16x8 aq[2];
#pragma unroll
    for (int ks = 0; ks < 2; ++ks)
        aq[ks] = *(const bf16x8*)(qg + (size_t)rowq * 64 + (ks * 4 + quad) * 8);
    bf16x8 ab1 = *(const bf16x8*)(b1b + ((size_t)(h * 1024 + q0 + rowq)) * 32 + quad * 8);

    // ones A-fragment for the row-sum MFMA
    bf16x8 onesv;
    {
        union { ushort_t u[8]; bf16x8 v; } c;
#pragma unroll
        for (int j = 0; j < 8; ++j) c.u[j] = 0x3F80;
        onesv = c.v;
    }

    const f32x4 mC = {NEG8L, NEG8L, NEG8L, NEG8L};
    const f32x4 z4 = {0.f, 0.f, 0.f, 0.f};
    f32x4 o[4];          // O^T: o[dt][r] = O[q=l15][d=dt*16+quad*4+r]
    f32x4 ls = z4;       // row-sum accumulator (all rows identical; col=q)
#pragma unroll
    for (int d = 0; d < 4; ++d) o[d] = z4;

    const int arow = lane >> 3;     // k staging: row within 8-row chunk
    const int ablk = lane & 7;
    const int arow4 = lane >> 4;    // v staging: row within 4-row chunk
    const int ablk16 = lane & 15;
    const int nbase = sp * 2048;
    ushort_t* pw = &pB[wave][0];

    for (int nt = 0; nt < 16; ++nt) {
        const int n0 = nbase + nt * 128;
        __syncthreads();
#pragma unroll
        for (int i = 0; i < 4; ++i) {
            int c = wave * 4 + i;
            int krow = c * 8 + arow;
            gld16(kg + (size_t)(n0 + krow) * 64 + (ablk ^ (krow & 7)) * 8,
                  (void*)(k_s + c * 512));
            int vrow = c * 4 + arow4;
            gld16(vg + (size_t)vrow * 4096 + n0 + (ablk16 ^ (vrow & 15)) * 8,
                  (void*)(v_s + c * 512));
        }
        bf16x8 wf[8];
#pragma unroll
        for (int nb = 0; nb < 8; ++nb)
            wf[nb] = *(const bf16x8*)(wtab + (size_t)(n0 + nb * 16 + l15) * 32 + quad * 8);
        __syncthreads();

        // S^T = wtab·b1^T + K·Q^T - 8log2e   (col=q, row=n), 8 nb chains
        f32x4 s[8];
#pragma unroll
        for (int nb = 0; nb < 8; ++nb) {
            s[nb] = __builtin_amdgcn_mfma_f32_16x16x32_bf16(wf[nb], ab1, mC, 0, 0, 0);
            int rn = nb * 16 + l15;
#pragma unroll
            for (int ks = 0; ks < 2; ++ks) {
                bf16x8 bk = *(const bf16x8*)(k_s + rn * 64 + (((ks * 4 + quad) ^ (rn & 7)) * 8));
                s[nb] = __builtin_amdgcn_mfma_f32_16x16x32_bf16(bk, aq[ks], s[nb], 0, 0, 0);
            }
        }
        // p = exp2(s); pk-pack 4 bf16 (n-consecutive) and write P^T[q][n]
#pragma unroll
        for (int nb = 0; nb < 8; ++nb) {
            *(us4*)(pw + l15 * 136 + nb * 16 + quad * 4) =
                pk4(fexp2(s[nb][0]), fexp2(s[nb][1]), fexp2(s[nb][2]), fexp2(s[nb][3]));
        }
        // PV: O^T += V^T · P^T ; row sums via ones·P^T on the same B-frags
#pragma unroll
        for (int ks = 0; ks < 4; ++ks) {
            bf16x8 bp = *(const bf16x8*)(pw + l15 * 136 + ks * 32 + quad * 8);
            ls = __builtin_amdgcn_mfma_f32_16x16x32_bf16(onesv, bp, ls, 0, 0, 0);
#pragma unroll
            for (int dt = 0; dt < 4; ++dt) {
                int rd = dt * 16 + l15;
                bf16x8 av = *(const bf16x8*)(v_s + rd * 128 + (((ks * 4 + quad) ^ (rd & 15)) * 8));
                o[dt] = __builtin_amdgcn_mfma_f32_16x16x32_bf16(av, bp, o[dt], 0, 0, 0);
            }
        }
    }

    const size_t pbase = ((size_t)(sp * 24 + bh)) * 1024;
    const int qrow = q0 + wave * 16 + l15;
    if (lane < 16) pl[pbase + qrow] = ls[0];   // every row of ls is the sum
#pragma unroll
    for (int dt = 0; dt < 4; ++dt)
        *(float4*)(po + (pbase + qrow) * 64 + dt * 16 + quad * 4) = (float4){o[dt][0], o[dt][1], o[dt][2], o[dt][3]};
}

// ----------------------------------------------------------- split combine
__global__ __launch_bounds__(256) void combine(const float* __restrict__ po,
                                               const float* __restrict__ pl,
                                               ushort_t* __restrict__ ab) {
    int idx = blockIdx.x * 256 + threadIdx.x;
    int e = idx * 4;
    int b = e / 786432;
    int rem = e - b * 786432;
    int q = rem / 768;
    int col = rem - q * 768;
    int h = col >> 6, d = col & 63;
    int bh = b * 12 + h;
    float4 acc = {0.f, 0.f, 0.f, 0.f};
    float l = 0.f;
#pragma unroll
    for (int s = 0; s < 2; ++s) {
        size_t base = ((size_t)(s * 24 + bh)) * 1024 + q;
        float4 v = *(const float4*)(po + base * 64 + d);
        acc.x += v.x; acc.y += v.y; acc.z += v.z; acc.w += v.w;
        l += pl[base];
    }
    float inv = 1.0f / l;
    *(us4*)(ab + (size_t)(b * 1024 + q) * 768 + col) =
        pk4(acc.x * inv, acc.y * inv, acc.z * inv, acc.w * inv);
}

// ------------------------------------------------------------------- launch
extern "C" void kernel_launch(void* const* d_in, const int* in_sizes, int n_in,
                              void* d_out, int out_size, void* d_ws, size_t ws_size,
                              hipStream_t stream) {
    const float* query = (const float*)d_in[0];
    const float* keyv  = (const float*)d_in[1];
    const float* Wq = (const float*)d_in[2];
    const float* bq = (const float*)d_in[3];
    const float* Wk = (const float*)d_in[4];
    const float* bk = (const float*)d_in[5];
    const float* Wv = (const float*)d_in[6];
    const float* bv = (const float*)d_in[7];
    const float* Wo = (const float*)d_in[8];
    const float* bo = (const float*)d_in[9];
    const float* rel = (const float*)d_in[10];

    char* ws = (char*)d_ws;
    ushort_t* qc   = (ushort_t*)(ws + 0);
    ushort_t* kvc  = (ushort_t*)(ws + 3145728);
    ushort_t* wtq  = (ushort_t*)(ws + 15728640);
    ushort_t* wtk  = (ushort_t*)(ws + 16908288);
    ushort_t* wtv  = (ushort_t*)(ws + 18087936);
    ushort_t* wto  = (ushort_t*)(ws + 19267584);
    ushort_t* qp   = (ushort_t*)(ws + 20447232);  // [B,H,Q,64] bf16 (x0.125*log2e)
    ushort_t* kp   = (ushort_t*)(ws + 23592960);  // [B,H,N,64] bf16
    ushort_t* vtp  = (ushort_t*)(ws + 36175872);  // [B,H,64,N] bf16
    ushort_t* b1b  = (ushort_t*)(ws + 48758784);  // [H,Q,32] bf16 (x log2e)
    ushort_t* wtab = (ushort_t*)(ws + 49545216);  // [N,32] bf16
    ushort_t* ab   = (ushort_t*)(ws + 49807360);  // [B,Q,768] bf16
    float*    po   = (float*)(ws + 52953088);     // [2,B*H,Q,64] f32 (12.6 MB)
    float*    pl   = (float*)(ws + 65536000);     // [2,B*H,Q] f32
    // total ws usage: ~65.7 MB

    prep<<<11536, 256, 0, stream>>>(query, keyv, Wq, Wk, Wv, Wo, rel,
                                    qc, kvc, wtq, wtk, wtv, wto, b1b, wtab);
    proj3<<<864, 256, 0, stream>>>(qc, kvc, wtq, wtk, wtv, bq, bk, bv, qp, kp, vtp);
    attn64s<<<768, 256, 0, stream>>>(qp, kp, vtp, b1b, wtab, po, pl);
    combine<<<1536, 256, 0, stream>>>(po, pl, ab);
    gemm_out<<<384, 256, 0, stream>>>(ab, wto, bo, (float*)d_out);
}